// Round 7
// baseline (1114.325 us; speedup 1.0000x reference)
//
#include <hip/hip_runtime.h>
#include <hip/hip_bf16.h>
#include <stdint.h>

// WindowAttention block for MI355X (gfx950). Round 7.
// CONFIRMED: inputs fp32, OUTPUT fp32 (round-6 identity probe: the "bf16" in
// the harness label is hardcoded text; bf16 writes were read as fp32 pairs ->
// stride-2 shear -> the 7.8 decorrelation of rounds 3-5).
// Pipeline: fp32 weights -> transposed bf16; x -> bf16 (d_out lower);
// QKV GEMM (MFMA) -> naive windowed attn (O bf16, d_out upper) ->
// LN1 -> x1 bf16 (ws) -> FFN halves (Hh bf16 ws; F fp32 IN d_out) ->
// LN2 in-place fp32 on d_out.
// ws peak 123,744,256 B (<= 130 MB confirmed by round-6 tripwire).

typedef __attribute__((ext_vector_type(4))) float f32x4;
typedef __attribute__((ext_vector_type(8))) short bf16x8;
typedef __attribute__((ext_vector_type(4))) short bf16x4;

__device__ __forceinline__ void async_cp16(const void* g, void* l) {
    __builtin_amdgcn_global_load_lds(
        (const __attribute__((address_space(1))) void*)g,
        (__attribute__((address_space(3))) void*)l,
        16, 0, 0);
}

__device__ __forceinline__ short f2bf(float f) {
    __hip_bfloat16 h = __float2bfloat16(f);
    return __builtin_bit_cast(short, h);
}
__device__ __forceinline__ float bf2f(short s) {
    return __bfloat162float(__builtin_bit_cast(__hip_bfloat16, s));
}

// ------------- GEMM: C[MxN] = A[MxK] * Bt[NxK]^T + bias -------------------
// A, Bt bf16. MODE 0: C bf16 (+bias, optional RELU). MODE 1: C fp32 (+bias).
// MODE 2: C fp32 += acc (accumulate in place; each block touches own tile).
template <int RELU, int MODE>
__global__ __launch_bounds__(256, 2) void gemm_kernel(
    const short* __restrict__ A, int lda,
    const short* __restrict__ Bt, int ldb,
    const float* __restrict__ bias,
    void* __restrict__ Cv, int ldc,
    int M, int N, int K)
{
    __shared__ __align__(16) short lds[8192]; // At[128][32] | Bts[128][32]
    short* At  = lds;
    short* Bts = lds + 4096;

    const int t = threadIdx.x;
    const int wave = t >> 6, lane = t & 63;
    const int quad = lane >> 4, l16 = lane & 15;
    const int wx = wave & 1, wy = wave >> 1;
    const long m0 = (long)blockIdx.x * 128;
    const long n0 = (long)blockIdx.y * 128;

    const int sr = t >> 2;           // staging row 0..63
    const int sc = (t & 3) << 3;     // staging col 0,8,16,24

    const short* ga = A  + (m0 + sr) * (long)lda + sc;
    const short* gb = Bt + (n0 + sr) * (long)ldb + sc;
    short* la0 = At  + wave * 512;          // wave-uniform LDS bases
    short* la1 = At  + 2048 + wave * 512;
    short* lb0 = Bts + wave * 512;
    short* lb1 = Bts + 2048 + wave * 512;

    f32x4 acc[4][4] = {};

    for (int k0 = 0; k0 < K; k0 += 32) {
        async_cp16(ga + k0,                  la0);
        async_cp16(ga + (long)64 * lda + k0, la1);
        async_cp16(gb + k0,                  lb0);
        async_cp16(gb + (long)64 * ldb + k0, lb1);
        __syncthreads();

        bf16x8 af[4], bfr[4];
#pragma unroll
        for (int i = 0; i < 4; ++i)
            af[i] = *(const bf16x8*)(At + (wy * 64 + i * 16 + l16) * 32 + quad * 8);
#pragma unroll
        for (int i = 0; i < 4; ++i)
            bfr[i] = *(const bf16x8*)(Bts + (wx * 64 + i * 16 + l16) * 32 + quad * 8);
#pragma unroll
        for (int mi = 0; mi < 4; ++mi)
#pragma unroll
            for (int ni = 0; ni < 4; ++ni)
                acc[mi][ni] = __builtin_amdgcn_mfma_f32_16x16x32_bf16(
                    af[mi], bfr[ni], acc[mi][ni], 0, 0, 0);
        __syncthreads();
    }

#pragma unroll
    for (int mi = 0; mi < 4; ++mi) {
#pragma unroll
        for (int ni = 0; ni < 4; ++ni) {
            const int n = (int)n0 + wx * 64 + ni * 16 + l16;
            const float bv = (MODE == 2) ? 0.f : bias[n];
#pragma unroll
            for (int r = 0; r < 4; ++r) {
                const long m = m0 + wy * 64 + mi * 16 + quad * 4 + r;
                float v = acc[mi][ni][r] + bv;
                if (MODE == 0) {
                    if (RELU) v = fmaxf(v, 0.f);
                    ((short*)Cv)[m * ldc + n] = f2bf(v);
                } else if (MODE == 1) {
                    ((float*)Cv)[m * ldc + n] = v;
                } else {
                    ((float*)Cv)[m * ldc + n] += v;   // own element, race-free
                }
            }
        }
    }
}

// -------- NAIVE windowed attention: one block per 64-token window ---------
// QKV: M x 3072 bf16 (Q|K|V). O: M x 1024 bf16.
__global__ __launch_bounds__(256, 2) void attn_naive_kernel(
    const short* __restrict__ QKV, short* __restrict__ O)
{
    __shared__ float Sf[64 * 65];
    const int t = threadIdx.x;
    const long rowbase = (long)blockIdx.x * 64;
    const short* Qg = QKV + rowbase * 3072;
    const short* Kg = Qg + 1024;
    const short* Vg = Qg + 2048;

    // phase 1: scores S[q][k] = (Q[q] . K[k]) * E^-0.5
    for (int p = t; p < 4096; p += 256) {
        const int q = p >> 6, k = p & 63;
        const short* qr = Qg + (long)q * 3072;
        const short* kr = Kg + (long)k * 3072;
        float acc = 0.f;
        for (int e = 0; e < 1024; e += 8) {
            bf16x8 qa = *(const bf16x8*)(qr + e);
            bf16x8 ka = *(const bf16x8*)(kr + e);
#pragma unroll
            for (int j = 0; j < 8; ++j) acc += bf2f(qa[j]) * bf2f(ka[j]);
        }
        Sf[q * 65 + k] = acc * 0.03125f;
    }
    __syncthreads();

    // phase 2: row softmax (fp32, in place), threads 0..63
    if (t < 64) {
        float mx = -1e30f;
        for (int j = 0; j < 64; ++j) mx = fmaxf(mx, Sf[t * 65 + j]);
        float sum = 0.f;
        for (int j = 0; j < 64; ++j) {
            float e = __expf(Sf[t * 65 + j] - mx);
            Sf[t * 65 + j] = e;
            sum += e;
        }
        const float inv = 1.f / sum;
        for (int j = 0; j < 64; ++j) Sf[t * 65 + j] *= inv;
    }
    __syncthreads();

    // phase 3: O[q][f] = sum_k P[q][k] * V[k][f]; thread covers f = t*4..+3
    for (int q = 0; q < 64; ++q) {
        float acc[4] = {0.f, 0.f, 0.f, 0.f};
        for (int k = 0; k < 64; ++k) {
            const float p = Sf[q * 65 + k];
            bf16x4 vv = *(const bf16x4*)(Vg + (long)k * 3072 + t * 4);
#pragma unroll
            for (int j = 0; j < 4; ++j) acc[j] += p * bf2f(vv[j]);
        }
        bf16x4 o;
#pragma unroll
        for (int j = 0; j < 4; ++j) o[j] = f2bf(acc[j]);
        *(bf16x4*)(O + (rowbase + q) * 1024 + t * 4) = o;
    }
}

// ------------- LN1: x1 = LN(x_fp32 + O_bf16) * g + b -> bf16 --------------
__global__ __launch_bounds__(256, 4) void ln1_kernel(
    const float* __restrict__ X, const short* __restrict__ R,
    const float* __restrict__ gamma, const float* __restrict__ beta,
    short* __restrict__ Y)
{
    __shared__ float red[8];
    const int t = threadIdx.x;
    const int wave = t >> 6, lane = t & 63;
    const long row = blockIdx.x;

    f32x4 xv = *(const f32x4*)(X + row * 1024 + t * 4);
    bf16x4 rv = *(const bf16x4*)(R + row * 1024 + t * 4);
    float v[4];
    float s = 0.f, sq = 0.f;
#pragma unroll
    for (int i = 0; i < 4; ++i) {
        v[i] = xv[i] + bf2f(rv[i]);
        s += v[i];
        sq += v[i] * v[i];
    }
#pragma unroll
    for (int off = 32; off > 0; off >>= 1) {
        s  += __shfl_down(s, off, 64);
        sq += __shfl_down(sq, off, 64);
    }
    if (lane == 0) { red[wave] = s; red[4 + wave] = sq; }
    __syncthreads();
    if (t == 0) {
        float S = red[0] + red[1] + red[2] + red[3];
        float Q = red[4] + red[5] + red[6] + red[7];
        float mean = S * (1.f / 1024.f);
        float var = fmaxf(Q * (1.f / 1024.f) - mean * mean, 0.f);
        red[0] = mean;
        red[1] = rsqrtf(var + 1e-5f);
    }
    __syncthreads();
    const float mean = red[0], rstd = red[1];
    f32x4 gv = *(const f32x4*)(gamma + t * 4);
    f32x4 bv = *(const f32x4*)(beta + t * 4);
    bf16x4 yv;
#pragma unroll
    for (int i = 0; i < 4; ++i)
        yv[i] = f2bf((v[i] - mean) * rstd * gv[i] + bv[i]);
    *(bf16x4*)(Y + row * 1024 + t * 4) = yv;
}

// ------ LN2: out = LN(x1_bf16 + F_fp32) * g + b -> fp32, in place on F ----
__global__ __launch_bounds__(256, 4) void ln2_kernel(
    const short* __restrict__ X1, float* __restrict__ F,
    const float* __restrict__ gamma, const float* __restrict__ beta)
{
    __shared__ float red[8];
    const int t = threadIdx.x;
    const int wave = t >> 6, lane = t & 63;
    const long row = blockIdx.x;

    bf16x4 xv = *(const bf16x4*)(X1 + row * 1024 + t * 4);
    f32x4 fv = *(const f32x4*)(F + row * 1024 + t * 4);
    float v[4];
    float s = 0.f, sq = 0.f;
#pragma unroll
    for (int i = 0; i < 4; ++i) {
        v[i] = bf2f(xv[i]) + fv[i];
        s += v[i];
        sq += v[i] * v[i];
    }
#pragma unroll
    for (int off = 32; off > 0; off >>= 1) {
        s  += __shfl_down(s, off, 64);
        sq += __shfl_down(sq, off, 64);
    }
    if (lane == 0) { red[wave] = s; red[4 + wave] = sq; }
    __syncthreads();
    if (t == 0) {
        float S = red[0] + red[1] + red[2] + red[3];
        float Q = red[4] + red[5] + red[6] + red[7];
        float mean = S * (1.f / 1024.f);
        float var = fmaxf(Q * (1.f / 1024.f) - mean * mean, 0.f);
        red[0] = mean;
        red[1] = rsqrtf(var + 1e-5f);
    }
    __syncthreads();
    const float mean = red[0], rstd = red[1];
    f32x4 gv = *(const f32x4*)(gamma + t * 4);
    f32x4 bv = *(const f32x4*)(beta + t * 4);
    f32x4 yv;
#pragma unroll
    for (int i = 0; i < 4; ++i)
        yv[i] = (v[i] - mean) * rstd * gv[i] + bv[i];
    *(f32x4*)(F + row * 1024 + t * 4) = yv;   // own row: in-place safe
}

// --------- weight transpose + cast: W[KxN] fp32 -> WT[NxK] bf16 -----------
__global__ __launch_bounds__(256, 2) void transpose_kernel(
    const float* __restrict__ W, short* __restrict__ WT, int K, int N)
{
    __shared__ __align__(16) short tile[64 * 72];
    const int t = threadIdx.x;
    const long kb = (long)blockIdx.x * 64, nb = (long)blockIdx.y * 64;
    const int r = t >> 3, c = (t & 7) << 3;
#pragma unroll
    for (int i = 0; i < 2; ++i) {
        f32x4 v0 = *(const f32x4*)(W + (kb + r + i * 32) * N + nb + c);
        f32x4 v1 = *(const f32x4*)(W + (kb + r + i * 32) * N + nb + c + 4);
        short* dst = tile + (r + i * 32) * 72 + c;
#pragma unroll
        for (int j = 0; j < 4; ++j) { dst[j] = f2bf(v0[j]); dst[4 + j] = f2bf(v1[j]); }
    }
    __syncthreads();
#pragma unroll
    for (int i = 0; i < 2; ++i) {
        const int rr = r + i * 32;      // n-index within tile
        bf16x8 o;
#pragma unroll
        for (int j = 0; j < 8; ++j) o[j] = tile[(c + j) * 72 + rr];
        *(bf16x8*)(WT + (nb + rr) * K + kb + c) = o;
    }
}

// --------------- x fp32 -> bf16 (into d_out lower half) -------------------
__global__ __launch_bounds__(256, 4) void cvt_kernel(
    const float* __restrict__ X, short* __restrict__ Y)
{
    const long i = ((long)blockIdx.x * 256 + threadIdx.x) * 4;
    f32x4 v = *(const f32x4*)(X + i);
    bf16x4 o;
#pragma unroll
    for (int j = 0; j < 4; ++j) o[j] = f2bf(v[j]);
    *(bf16x4*)(Y + i) = o;
}

__global__ void concat_bias_kernel(const float* __restrict__ bq,
                                   const float* __restrict__ bk,
                                   const float* __restrict__ bv,
                                   float* __restrict__ out)
{
    const int i = blockIdx.x * 256 + threadIdx.x;   // 0..3071
    float v;
    if (i < 1024)      v = bq[i];
    else if (i < 2048) v = bk[i - 1024];
    else               v = bv[i - 2048];
    out[i] = v;
}

extern "C" void kernel_launch(void* const* d_in, const int* in_sizes, int n_in,
                              void* d_out, int out_size, void* d_ws, size_t ws_size,
                              hipStream_t stream)
{
    const float* x   = (const float*)d_in[0];
    const float* Wq  = (const float*)d_in[1];
    const float* bq  = (const float*)d_in[2];
    const float* Wk  = (const float*)d_in[3];
    const float* bk  = (const float*)d_in[4];
    const float* Wv  = (const float*)d_in[5];
    const float* bv  = (const float*)d_in[6];
    const float* g1  = (const float*)d_in[7];
    const float* be1 = (const float*)d_in[8];
    const float* W1  = (const float*)d_in[9];
    const float* b1  = (const float*)d_in[10];
    const float* W2  = (const float*)d_in[11];
    const float* b2  = (const float*)d_in[12];
    const float* g2  = (const float*)d_in[13];
    const float* be2 = (const float*)d_in[14];

    const int M = in_sizes[0] / 1024;        // 16384 tokens
    float* F    = (float*)d_out;             // fp32 pre-LN2 sum & final out (64 MB)
    short* xbf  = (short*)d_out;             // bf16 x, lower 32 MB (dead after QKV)
    short* Obf  = (short*)d_out + (size_t)M * 1024;  // bf16 attn O, upper 32 MB

    // workspace layout (bytes); peak 123,744,256
    char* ws = (char*)d_ws;
    short* WqkvT = (short*)ws;                     // [0, 6291456)
    short* W1T   = (short*)(ws + 6291456);         // [.., 14680064)
    short* W2T   = (short*)(ws + 14680064);        // [.., 23068672)
    float* bqkv  = (float*)(ws + 23068672);        // [.., 23080960)
    short* QKV   = (short*)(ws + 23080960);        // M x 3072 bf16 (96 MB)
    short* Hh    = (short*)(ws + 23080960);        // M x 2048 bf16, overlays QKV[0:64MB)
    short* x1    = (short*)(ws + 23080960 + (size_t)M * 2048 * 2); // M x 1024 bf16, QKV[64:96MB)

    dim3 blk(256);
    // weight prep (fp32 -> transposed bf16)
    transpose_kernel<<<dim3(16, 16), blk, 0, stream>>>(Wq, WqkvT,               1024, 1024);
    transpose_kernel<<<dim3(16, 16), blk, 0, stream>>>(Wk, WqkvT + 1024 * 1024, 1024, 1024);
    transpose_kernel<<<dim3(16, 16), blk, 0, stream>>>(Wv, WqkvT + 2048 * 1024, 1024, 1024);
    transpose_kernel<<<dim3(16, 64), blk, 0, stream>>>(W1, W1T, 1024, 4096);
    transpose_kernel<<<dim3(64, 16), blk, 0, stream>>>(W2, W2T, 4096, 1024);
    concat_bias_kernel<<<12, blk, 0, stream>>>(bq, bk, bv, bqkv);
    cvt_kernel<<<M, blk, 0, stream>>>(x, xbf);

    // QKV = x_bf @ Wqkv + bqkv  (bf16 out)
    gemm_kernel<0, 0><<<dim3(M / 128, 24), blk, 0, stream>>>(
        xbf, 1024, WqkvT, 1024, bqkv, QKV, 3072, M, 3072, 1024);
    // windowed attention -> O (d_out upper half; xbf now dead)
    attn_naive_kernel<<<M / 64, blk, 0, stream>>>(QKV, Obf);
    // x1 = LN(x + O) -> bf16 in ws (QKV dead from here)
    ln1_kernel<<<M, blk, 0, stream>>>(x, Obf, g1, be1, x1);
    // FFN half a: Hh = relu(x1 @ W1[:, :2048]); F = Hh @ W2[:2048, :] + b2 (fp32)
    gemm_kernel<1, 0><<<dim3(M / 128, 16), blk, 0, stream>>>(
        x1, 1024, W1T, 1024, b1, Hh, 2048, M, 2048, 1024);
    gemm_kernel<0, 1><<<dim3(M / 128, 8), blk, 0, stream>>>(
        Hh, 2048, W2T, 4096, b2, F, 1024, M, 1024, 2048);
    // FFN half b: Hh = relu(x1 @ W1[:, 2048:]); F += Hh @ W2[2048:, :]
    gemm_kernel<1, 0><<<dim3(M / 128, 16), blk, 0, stream>>>(
        x1, 1024, W1T + 2048 * 1024, 1024, b1 + 2048, Hh, 2048, M, 2048, 1024);
    gemm_kernel<0, 2><<<dim3(M / 128, 8), blk, 0, stream>>>(
        Hh, 2048, W2T + 2048, 4096, b2, F, 1024, M, 1024, 2048);
    // out = LN(x1 + F) -> fp32, in place on F (= d_out)
    ln2_kernel<<<M, blk, 0, stream>>>(x1, F, g2, be2);
}